// Round 2
// baseline (705.326 us; speedup 1.0000x reference)
//
#include <hip/hip_runtime.h>
#include <stdint.h>

#define HD 8
#define DD 64
#define CAP 64   // per-node direct edge-list capacity (mean degree = 32)

// Native clang vector types — required by __builtin_nontemporal_load/store.
typedef float  vf4 __attribute__((ext_vector_type(4)));

// Monotone float->uint mapping so unsigned atomicMax implements float max.
__device__ __forceinline__ unsigned fmap(float f) {
    unsigned u = __float_as_uint(f);
    return u ^ (unsigned)(((int)u >> 31) | 0x80000000);
}
__device__ __forceinline__ float funmap(unsigned u) {
    u ^= ((int)u < 0) ? 0x80000000u : 0xFFFFFFFFu;
    return __uint_as_float(u);
}
#define FMAP_NEG_INF 0x007FFFFFu   // maps back to -inf

// bf16 helpers. Slot layout per node (4 u32 words): word g = (bf16 h=g) | (bf16 h=g+4)<<16.
__device__ __forceinline__ unsigned pack_bf16_rne(float a, float b) {
    unsigned ua = __float_as_uint(a); ua += 0x7FFF + ((ua >> 16) & 1);
    unsigned ub = __float_as_uint(b); ub += 0x7FFF + ((ub >> 16) & 1);
    return (ua >> 16) | (ub & 0xFFFF0000u);
}
__device__ __forceinline__ float bf_lo(unsigned u) { return __uint_as_float(u << 16); }
__device__ __forceinline__ float bf_hi(unsigned u) { return __uint_as_float(u & 0xFFFF0000u); }

// Phase A: t_pk[n] = packed bf16 tanh(X[n,h,:] . W[:,h]); init m_u slots to mapped(-inf);
// zero the per-node edge counters (cnt may be null on the fallback path).
__global__ __launch_bounds__(256) void attn_tanh_kernel(
    const float* __restrict__ X, const float* __restrict__ Wk,
    unsigned* __restrict__ t_pk, uint2* __restrict__ m_init,
    unsigned* __restrict__ cnt, int N)
{
    __shared__ float Ws[DD * HD];   // W[d*8+h], 2 KB
    int tid = threadIdx.x;
    for (int i = tid; i < DD * HD; i += 256) Ws[i] = Wk[i];

    int gid = blockIdx.x * 256 + tid;           // grid has >= N threads (N/8 blocks * 256)
    if (cnt != nullptr && gid < N) cnt[gid] = 0;

    __syncthreads();

    int wave = tid >> 6, lane = tid & 63;
    int n0 = (blockIdx.x * 4 + wave) * 2;
    if (n0 >= N) return;
    bool two = (n0 + 1 < N);

    const vf4* Xa = (const vf4*)X + (size_t)n0 * 128;  // 512 floats/node
    vf4 z = {0.f, 0.f, 0.f, 0.f};
    vf4 xv0 = __builtin_nontemporal_load(Xa + lane);
    vf4 xv1 = __builtin_nontemporal_load(Xa + 64 + lane);
    vf4 xv2 = two ? __builtin_nontemporal_load(Xa + 128 + lane) : z;
    vf4 xv3 = two ? __builtin_nontemporal_load(Xa + 192 + lane) : z;

    int h0 = lane >> 4, d0 = (lane & 15) << 2;
    int h1 = 4 + h0;
    float w00 = Ws[(d0 + 0) * HD + h0], w01 = Ws[(d0 + 1) * HD + h0],
          w02 = Ws[(d0 + 2) * HD + h0], w03 = Ws[(d0 + 3) * HD + h0];
    float w10 = Ws[(d0 + 0) * HD + h1], w11 = Ws[(d0 + 1) * HD + h1],
          w12 = Ws[(d0 + 2) * HD + h1], w13 = Ws[(d0 + 3) * HD + h1];

    float p0 = xv0.x * w00 + xv0.y * w01 + xv0.z * w02 + xv0.w * w03;
    float p1 = xv1.x * w10 + xv1.y * w11 + xv1.z * w12 + xv1.w * w13;
    float p2 = xv2.x * w00 + xv2.y * w01 + xv2.z * w02 + xv2.w * w03;
    float p3 = xv3.x * w10 + xv3.y * w11 + xv3.z * w12 + xv3.w * w13;

    for (int off = 8; off; off >>= 1) {
        p0 += __shfl_xor(p0, off);
        p1 += __shfl_xor(p1, off);
        p2 += __shfl_xor(p2, off);
        p3 += __shfl_xor(p3, off);
    }
    if ((lane & 15) == 0) {
        int g = lane >> 4;
        t_pk[(size_t)n0 * 4 + g] = pack_bf16_rne(tanhf(p0), tanhf(p1));
        m_init[(size_t)n0 * 4 + g] = make_uint2(FMAP_NEG_INF, FMAP_NEG_INF);
        if (two) {
            t_pk[(size_t)(n0 + 1) * 4 + g] = pack_bf16_rne(tanhf(p2), tanhf(p3));
            m_init[(size_t)(n0 + 1) * 4 + g] = make_uint2(FMAP_NEG_INF, FMAP_NEG_INF);
        }
    }
}

// Phase B: assign each edge a slot in its target's fixed-capacity source list.
// One atomicAdd per edge (vs 8 atomicMax candidates before). Overflow (deg > CAP,
// expected ~0 nodes for Poisson(32)) falls back to exact atomicMax into m_u.
__global__ __launch_bounds__(256) void scatter_kernel(
    const int* __restrict__ sources, const int* __restrict__ targets,
    unsigned* __restrict__ cnt, unsigned* __restrict__ lst,
    const uint4* __restrict__ t_pk4, unsigned* __restrict__ m_u, int E)
{
    int e = blockIdx.x * 256 + threadIdx.x;
    if (e >= E) return;
    int s  = __builtin_nontemporal_load(sources + e);
    int tg = __builtin_nontemporal_load(targets + e);
    unsigned pos = atomicAdd(cnt + tg, 1u);
    if (pos < CAP) {
        lst[(size_t)tg * CAP + pos] = (unsigned)s;
    } else {
        // rare exact fallback, slot order [h0,h4,h1,h5,h2,h6,h3,h7]
        uint4 tv = t_pk4[s];
        unsigned* mp = m_u + (size_t)tg * HD;
        atomicMax(mp + 0, fmap(bf_lo(tv.x)));
        atomicMax(mp + 1, fmap(bf_hi(tv.x)));
        atomicMax(mp + 2, fmap(bf_lo(tv.y)));
        atomicMax(mp + 3, fmap(bf_hi(tv.y)));
        atomicMax(mp + 4, fmap(bf_lo(tv.z)));
        atomicMax(mp + 5, fmap(bf_hi(tv.z)));
        atomicMax(mp + 6, fmap(bf_lo(tv.w)));
        atomicMax(mp + 7, fmap(bf_hi(tv.w)));
    }
}

// Phase B2: per-node gather-max, zero atomics. One wave per node; lane l reads
// list entry l (CAP == 64 == wavefront), gathers t_pk (L2-resident 1.6 MB), shuffle-
// reduces 8 head maxes, combines rare m_u overflow values, writes bf16 m_pk directly
// (absorbs the old pack_m kernel).
__global__ __launch_bounds__(256) void gather_max_kernel(
    const unsigned* __restrict__ cnt, const unsigned* __restrict__ lst,
    const uint4* __restrict__ t_pk4, const unsigned* __restrict__ m_u,
    uint4* __restrict__ m_pk, int N)
{
    int wave = threadIdx.x >> 6, lane = threadIdx.x & 63;
    int n = blockIdx.x * 4 + wave;
    if (n >= N) return;

    unsigned c = cnt[n];          // same address across wave -> broadcast
    if (c > CAP) c = CAP;

    float v0 = -INFINITY, v1 = -INFINITY, v2 = -INFINITY, v3 = -INFINITY,
          v4 = -INFINITY, v5 = -INFINITY, v6 = -INFINITY, v7 = -INFINITY;
    if ((unsigned)lane < c) {
        unsigned s = lst[(size_t)n * CAP + lane];   // coalesced 256B segment
        uint4 tv = t_pk4[s];
        v0 = bf_lo(tv.x); v1 = bf_hi(tv.x);   // h0, h4
        v2 = bf_lo(tv.y); v3 = bf_hi(tv.y);   // h1, h5
        v4 = bf_lo(tv.z); v5 = bf_hi(tv.z);   // h2, h6
        v6 = bf_lo(tv.w); v7 = bf_hi(tv.w);   // h3, h7
    }
    for (int off = 32; off; off >>= 1) {
        v0 = fmaxf(v0, __shfl_xor(v0, off));
        v1 = fmaxf(v1, __shfl_xor(v1, off));
        v2 = fmaxf(v2, __shfl_xor(v2, off));
        v3 = fmaxf(v3, __shfl_xor(v3, off));
        v4 = fmaxf(v4, __shfl_xor(v4, off));
        v5 = fmaxf(v5, __shfl_xor(v5, off));
        v6 = fmaxf(v6, __shfl_xor(v6, off));
        v7 = fmaxf(v7, __shfl_xor(v7, off));
    }
    if (lane == 0) {
        const unsigned* mu = m_u + (size_t)n * HD;  // -inf unless overflow fallback fired
        v0 = fmaxf(v0, funmap(mu[0]));
        v1 = fmaxf(v1, funmap(mu[1]));
        v2 = fmaxf(v2, funmap(mu[2]));
        v3 = fmaxf(v3, funmap(mu[3]));
        v4 = fmaxf(v4, funmap(mu[4]));
        v5 = fmaxf(v5, funmap(mu[5]));
        v6 = fmaxf(v6, funmap(mu[6]));
        v7 = fmaxf(v7, funmap(mu[7]));
        uint4 o;                                    // lossless: maxes of bf16 values
        o.x = pack_bf16_rne(v0, v1);
        o.y = pack_bf16_rne(v2, v3);
        o.z = pack_bf16_rne(v4, v5);
        o.w = pack_bf16_rne(v6, v7);
        m_pk[n] = o;
    }
}

// ---- Fallback path (old, proven) kernels: used only if workspace is too small ----

__global__ __launch_bounds__(256) void seg_max_kernel(
    const int* __restrict__ sources, const int* __restrict__ targets,
    const uint4* __restrict__ t_pk4, unsigned* __restrict__ m_u, int E)
{
    int e = blockIdx.x * 256 + threadIdx.x;
    if (e >= E) return;
    int s  = __builtin_nontemporal_load(sources + e);
    int tg = __builtin_nontemporal_load(targets + e);
    uint4 tv = t_pk4[s];
    unsigned* mp = m_u + (size_t)tg * HD;
    const uint4* m4 = (const uint4*)mp;
    uint4 c0 = m4[0];
    uint4 c1 = m4[1];
    unsigned f;
    f = fmap(bf_lo(tv.x)); if (f > c0.x) atomicMax(mp + 0, f);
    f = fmap(bf_hi(tv.x)); if (f > c0.y) atomicMax(mp + 1, f);
    f = fmap(bf_lo(tv.y)); if (f > c0.z) atomicMax(mp + 2, f);
    f = fmap(bf_hi(tv.y)); if (f > c0.w) atomicMax(mp + 3, f);
    f = fmap(bf_lo(tv.z)); if (f > c1.x) atomicMax(mp + 4, f);
    f = fmap(bf_hi(tv.z)); if (f > c1.y) atomicMax(mp + 5, f);
    f = fmap(bf_lo(tv.w)); if (f > c1.z) atomicMax(mp + 6, f);
    f = fmap(bf_hi(tv.w)); if (f > c1.w) atomicMax(mp + 7, f);
}

__global__ __launch_bounds__(256) void pack_m_kernel(
    const unsigned* __restrict__ m_u, uint4* __restrict__ m_pk, int N)
{
    int n = blockIdx.x * 256 + threadIdx.x;
    if (n >= N) return;
    const uint4* mu4 = (const uint4*)m_u + (size_t)n * 2;
    uint4 c0 = mu4[0];
    uint4 c1 = mu4[1];
    uint4 o;
    o.x = (__float_as_uint(funmap(c0.x)) >> 16) | (__float_as_uint(funmap(c0.y)) & 0xFFFF0000u);
    o.y = (__float_as_uint(funmap(c0.z)) >> 16) | (__float_as_uint(funmap(c0.w)) & 0xFFFF0000u);
    o.z = (__float_as_uint(funmap(c1.x)) >> 16) | (__float_as_uint(funmap(c1.y)) & 0xFFFF0000u);
    o.w = (__float_as_uint(funmap(c1.z)) >> 16) | (__float_as_uint(funmap(c1.w)) & 0xFFFF0000u);
    m_pk[n] = o;
}

// Phase C: out[e,h] = exp(t[src,h] - m[tgt,h]) * drop_mask[e,h].
// (Reference's s = segment_max(exp(ef-m)) + 1e-9 == 1.0f exactly in fp32.)
__global__ __launch_bounds__(256) void finalize_kernel(
    const int* __restrict__ sources, const int* __restrict__ targets,
    const uint4* __restrict__ t_pk4, const uint4* __restrict__ m_pk,
    const float* __restrict__ dm, float* __restrict__ out, int E)
{
    int e = blockIdx.x * 256 + threadIdx.x;
    if (e >= E) return;
    int s  = __builtin_nontemporal_load(sources + e);
    int tg = __builtin_nontemporal_load(targets + e);
    uint4 tv = t_pk4[s];
    uint4 mv = m_pk[tg];
    const vf4* dm4 = (const vf4*)dm;
    vf4 d0 = __builtin_nontemporal_load(dm4 + (size_t)e * 2);      // heads 0..3
    vf4 d1 = __builtin_nontemporal_load(dm4 + (size_t)e * 2 + 1);  // heads 4..7
    vf4 o0, o1;
    o0.x = expf(bf_lo(tv.x) - bf_lo(mv.x)) * d0.x;  // h0
    o0.y = expf(bf_lo(tv.y) - bf_lo(mv.y)) * d0.y;  // h1
    o0.z = expf(bf_lo(tv.z) - bf_lo(mv.z)) * d0.z;  // h2
    o0.w = expf(bf_lo(tv.w) - bf_lo(mv.w)) * d0.w;  // h3
    o1.x = expf(bf_hi(tv.x) - bf_hi(mv.x)) * d1.x;  // h4
    o1.y = expf(bf_hi(tv.y) - bf_hi(mv.y)) * d1.y;  // h5
    o1.z = expf(bf_hi(tv.z) - bf_hi(mv.z)) * d1.z;  // h6
    o1.w = expf(bf_hi(tv.w) - bf_hi(mv.w)) * d1.w;  // h7
    vf4* out4 = (vf4*)out;
    __builtin_nontemporal_store(o0, out4 + (size_t)e * 2);
    __builtin_nontemporal_store(o1, out4 + (size_t)e * 2 + 1);
}

extern "C" void kernel_launch(void* const* d_in, const int* in_sizes, int n_in,
                              void* d_out, int out_size, void* d_ws, size_t ws_size,
                              hipStream_t stream)
{
    const float* X       = (const float*)d_in[0];   // (B,N,H,D) fp32
    const float* Wk      = (const float*)d_in[1];   // (D,H,1)   fp32
    const int*   targets = (const int*)d_in[2];     // (B,E)
    const int*   sources = (const int*)d_in[3];     // (B,E)
    const float* dm      = (const float*)d_in[5];   // (B,E,H)

    int E = in_sizes[2];          // B=1
    int N = in_sizes[4];          // degree is (B,N)

    float* out = (float*)d_out;
    int blocksA = (N + 7) / 8;           // 4 waves/block, 2 nodes/wave
    int blocksE = (E + 255) / 256;

    // New-path workspace layout (bytes):
    //   t_pk 16N | m_u 32N | m_pk 16N | cnt 4N | lst CAP*4*N = 256N   -> total 324N
    size_t needed = (size_t)N * 324;

    char* w = (char*)d_ws;
    unsigned* t_pk = (unsigned*)w;
    unsigned* m_u  = (unsigned*)(w + (size_t)N * 16);
    uint4*    m_pk = (uint4*)  (w + (size_t)N * 48);

    if (ws_size >= needed) {
        unsigned* cnt = (unsigned*)(w + (size_t)N * 64);
        unsigned* lst = (unsigned*)(w + (size_t)N * 68);

        attn_tanh_kernel<<<blocksA, 256, 0, stream>>>(X, Wk, t_pk, (uint2*)m_u, cnt, N);
        scatter_kernel<<<blocksE, 256, 0, stream>>>(sources, targets, cnt, lst,
                                                    (const uint4*)t_pk, m_u, E);
        int blocksG = (N + 3) / 4;       // one wave per node
        gather_max_kernel<<<blocksG, 256, 0, stream>>>(cnt, lst, (const uint4*)t_pk,
                                                       m_u, m_pk, N);
        finalize_kernel<<<blocksE, 256, 0, stream>>>(sources, targets, (const uint4*)t_pk,
                                                     m_pk, dm, out, E);
    } else {
        // Fallback: previous proven path (identical numerics).
        attn_tanh_kernel<<<blocksA, 256, 0, stream>>>(X, Wk, t_pk, (uint2*)m_u, nullptr, N);
        seg_max_kernel<<<blocksE, 256, 0, stream>>>(sources, targets, (const uint4*)t_pk, m_u, E);
        int blocksN = (N + 255) / 256;
        pack_m_kernel<<<blocksN, 256, 0, stream>>>(m_u, m_pk, N);
        finalize_kernel<<<blocksE, 256, 0, stream>>>(sources, targets, (const uint4*)t_pk,
                                                     m_pk, dm, out, E);
    }
}

// Round 3
// 701.452 us; speedup vs baseline: 1.0055x; 1.0055x over previous
//
#include <hip/hip_runtime.h>
#include <stdint.h>

#define HD 8
#define DD 64
#define CAP 64   // per-node direct edge-list capacity (mean degree = 32)

// Native clang vector types — required by __builtin_nontemporal_load/store.
typedef float  vf4 __attribute__((ext_vector_type(4)));

// Monotone float->uint mapping so unsigned atomicMax implements float max.
__device__ __forceinline__ unsigned fmap(float f) {
    unsigned u = __float_as_uint(f);
    return u ^ (unsigned)(((int)u >> 31) | 0x80000000);
}
__device__ __forceinline__ float funmap(unsigned u) {
    u ^= ((int)u < 0) ? 0x80000000u : 0xFFFFFFFFu;
    return __uint_as_float(u);
}
#define FMAP_NEG_INF 0x007FFFFFu   // maps back to -inf

// bf16 helpers. Slot layout per node (4 u32 words): word g = (bf16 h=g) | (bf16 h=g+4)<<16.
__device__ __forceinline__ unsigned pack_bf16_rne(float a, float b) {
    unsigned ua = __float_as_uint(a); ua += 0x7FFF + ((ua >> 16) & 1);
    unsigned ub = __float_as_uint(b); ub += 0x7FFF + ((ub >> 16) & 1);
    return (ua >> 16) | (ub & 0xFFFF0000u);
}
__device__ __forceinline__ float bf_lo(unsigned u) { return __uint_as_float(u << 16); }
__device__ __forceinline__ float bf_hi(unsigned u) { return __uint_as_float(u & 0xFFFF0000u); }

// Phase A: t_pk[n] = packed bf16 tanh(X[n,h,:] . W[:,h]); init m_u slots to mapped(-inf);
// zero the per-node edge counters (cnt may be null on the fallback path).
__global__ __launch_bounds__(256) void attn_tanh_kernel(
    const float* __restrict__ X, const float* __restrict__ Wk,
    unsigned* __restrict__ t_pk, uint2* __restrict__ m_init,
    unsigned* __restrict__ cnt, int N)
{
    __shared__ float Ws[DD * HD];   // W[d*8+h], 2 KB
    int tid = threadIdx.x;
    for (int i = tid; i < DD * HD; i += 256) Ws[i] = Wk[i];

    int gid = blockIdx.x * 256 + tid;           // grid has >= N threads (N/8 blocks * 256)
    if (cnt != nullptr && gid < N) cnt[gid] = 0;

    __syncthreads();

    int wave = tid >> 6, lane = tid & 63;
    int n0 = (blockIdx.x * 4 + wave) * 2;
    if (n0 >= N) return;
    bool two = (n0 + 1 < N);

    const vf4* Xa = (const vf4*)X + (size_t)n0 * 128;  // 512 floats/node
    vf4 z = {0.f, 0.f, 0.f, 0.f};
    vf4 xv0 = __builtin_nontemporal_load(Xa + lane);
    vf4 xv1 = __builtin_nontemporal_load(Xa + 64 + lane);
    vf4 xv2 = two ? __builtin_nontemporal_load(Xa + 128 + lane) : z;
    vf4 xv3 = two ? __builtin_nontemporal_load(Xa + 192 + lane) : z;

    int h0 = lane >> 4, d0 = (lane & 15) << 2;
    int h1 = 4 + h0;
    float w00 = Ws[(d0 + 0) * HD + h0], w01 = Ws[(d0 + 1) * HD + h0],
          w02 = Ws[(d0 + 2) * HD + h0], w03 = Ws[(d0 + 3) * HD + h0];
    float w10 = Ws[(d0 + 0) * HD + h1], w11 = Ws[(d0 + 1) * HD + h1],
          w12 = Ws[(d0 + 2) * HD + h1], w13 = Ws[(d0 + 3) * HD + h1];

    float p0 = xv0.x * w00 + xv0.y * w01 + xv0.z * w02 + xv0.w * w03;
    float p1 = xv1.x * w10 + xv1.y * w11 + xv1.z * w12 + xv1.w * w13;
    float p2 = xv2.x * w00 + xv2.y * w01 + xv2.z * w02 + xv2.w * w03;
    float p3 = xv3.x * w10 + xv3.y * w11 + xv3.z * w12 + xv3.w * w13;

    for (int off = 8; off; off >>= 1) {
        p0 += __shfl_xor(p0, off);
        p1 += __shfl_xor(p1, off);
        p2 += __shfl_xor(p2, off);
        p3 += __shfl_xor(p3, off);
    }
    if ((lane & 15) == 0) {
        int g = lane >> 4;
        t_pk[(size_t)n0 * 4 + g] = pack_bf16_rne(tanhf(p0), tanhf(p1));
        m_init[(size_t)n0 * 4 + g] = make_uint2(FMAP_NEG_INF, FMAP_NEG_INF);
        if (two) {
            t_pk[(size_t)(n0 + 1) * 4 + g] = pack_bf16_rne(tanhf(p2), tanhf(p3));
            m_init[(size_t)(n0 + 1) * 4 + g] = make_uint2(FMAP_NEG_INF, FMAP_NEG_INF);
        }
    }
}

// Phase B: assign each edge a slot in its target's source list. TRANSPOSED layout:
// lst[pos * N + tg]. Per pos-row the write working set is a dense 4B*N region, so
// lines stay L2-resident and merge (vs round-2 [tg][pos] layout: 193 MB of partial-
// line HBM writes for a 12.8 MB payload). Two edges per thread for atomic-return ILP.
// Overflow (deg > CAP) falls back to exact atomicMax into m_u.
__global__ __launch_bounds__(256) void scatter_kernel(
    const int* __restrict__ sources, const int* __restrict__ targets,
    unsigned* __restrict__ cnt, unsigned* __restrict__ lst,
    const uint4* __restrict__ t_pk4, unsigned* __restrict__ m_u, int N, int E)
{
    int e0 = (blockIdx.x * 256 + threadIdx.x) * 2;
    if (e0 >= E) return;
    bool two = (e0 + 1 < E);

    int s0  = __builtin_nontemporal_load(sources + e0);
    int tg0 = __builtin_nontemporal_load(targets + e0);
    int s1 = 0, tg1 = 0;
    if (two) {
        s1  = __builtin_nontemporal_load(sources + e0 + 1);
        tg1 = __builtin_nontemporal_load(targets + e0 + 1);
    }

    unsigned pos0 = atomicAdd(cnt + tg0, 1u);
    unsigned pos1 = two ? atomicAdd(cnt + tg1, 1u) : 0u;

    if (pos0 < CAP) {
        lst[(size_t)pos0 * N + tg0] = (unsigned)s0;
    } else {
        uint4 tv = t_pk4[s0];
        unsigned* mp = m_u + (size_t)tg0 * HD;
        atomicMax(mp + 0, fmap(bf_lo(tv.x)));
        atomicMax(mp + 1, fmap(bf_hi(tv.x)));
        atomicMax(mp + 2, fmap(bf_lo(tv.y)));
        atomicMax(mp + 3, fmap(bf_hi(tv.y)));
        atomicMax(mp + 4, fmap(bf_lo(tv.z)));
        atomicMax(mp + 5, fmap(bf_hi(tv.z)));
        atomicMax(mp + 6, fmap(bf_lo(tv.w)));
        atomicMax(mp + 7, fmap(bf_hi(tv.w)));
    }
    if (two) {
        if (pos1 < CAP) {
            lst[(size_t)pos1 * N + tg1] = (unsigned)s1;
        } else {
            uint4 tv = t_pk4[s1];
            unsigned* mp = m_u + (size_t)tg1 * HD;
            atomicMax(mp + 0, fmap(bf_lo(tv.x)));
            atomicMax(mp + 1, fmap(bf_hi(tv.x)));
            atomicMax(mp + 2, fmap(bf_lo(tv.y)));
            atomicMax(mp + 3, fmap(bf_hi(tv.y)));
            atomicMax(mp + 4, fmap(bf_lo(tv.z)));
            atomicMax(mp + 5, fmap(bf_hi(tv.z)));
            atomicMax(mp + 6, fmap(bf_lo(tv.w)));
            atomicMax(mp + 7, fmap(bf_hi(tv.w)));
        }
    }
}

// Phase B2: per-node gather-max, zero atomics. One wave per node; lane l reads
// transposed list entry lst[l*N + n]; consecutive node-waves share the same cache
// lines (16 nodes/line), so reads are L2-served after first touch. Shuffle-reduces
// 8 head maxes, merges rare m_u overflow values, writes bf16 m_pk directly.
__global__ __launch_bounds__(256) void gather_max_kernel(
    const unsigned* __restrict__ cnt, const unsigned* __restrict__ lst,
    const uint4* __restrict__ t_pk4, const unsigned* __restrict__ m_u,
    uint4* __restrict__ m_pk, int N)
{
    int wave = threadIdx.x >> 6, lane = threadIdx.x & 63;
    int n = blockIdx.x * 4 + wave;
    if (n >= N) return;

    unsigned c = cnt[n];          // same address across wave -> broadcast
    if (c > CAP) c = CAP;

    float v0 = -INFINITY, v1 = -INFINITY, v2 = -INFINITY, v3 = -INFINITY,
          v4 = -INFINITY, v5 = -INFINITY, v6 = -INFINITY, v7 = -INFINITY;
    if ((unsigned)lane < c) {
        unsigned s = lst[(size_t)lane * N + n];   // transposed read
        uint4 tv = t_pk4[s];
        v0 = bf_lo(tv.x); v1 = bf_hi(tv.x);   // h0, h4
        v2 = bf_lo(tv.y); v3 = bf_hi(tv.y);   // h1, h5
        v4 = bf_lo(tv.z); v5 = bf_hi(tv.z);   // h2, h6
        v6 = bf_lo(tv.w); v7 = bf_hi(tv.w);   // h3, h7
    }
    for (int off = 32; off; off >>= 1) {
        v0 = fmaxf(v0, __shfl_xor(v0, off));
        v1 = fmaxf(v1, __shfl_xor(v1, off));
        v2 = fmaxf(v2, __shfl_xor(v2, off));
        v3 = fmaxf(v3, __shfl_xor(v3, off));
        v4 = fmaxf(v4, __shfl_xor(v4, off));
        v5 = fmaxf(v5, __shfl_xor(v5, off));
        v6 = fmaxf(v6, __shfl_xor(v6, off));
        v7 = fmaxf(v7, __shfl_xor(v7, off));
    }
    if (lane == 0) {
        const unsigned* mu = m_u + (size_t)n * HD;  // -inf unless overflow fallback fired
        v0 = fmaxf(v0, funmap(mu[0]));
        v1 = fmaxf(v1, funmap(mu[1]));
        v2 = fmaxf(v2, funmap(mu[2]));
        v3 = fmaxf(v3, funmap(mu[3]));
        v4 = fmaxf(v4, funmap(mu[4]));
        v5 = fmaxf(v5, funmap(mu[5]));
        v6 = fmaxf(v6, funmap(mu[6]));
        v7 = fmaxf(v7, funmap(mu[7]));
        uint4 o;                                    // lossless: maxes of bf16 values
        o.x = pack_bf16_rne(v0, v1);
        o.y = pack_bf16_rne(v2, v3);
        o.z = pack_bf16_rne(v4, v5);
        o.w = pack_bf16_rne(v6, v7);
        m_pk[n] = o;
    }
}

// ---- Fallback path (old, proven) kernels: used only if workspace is too small ----

__global__ __launch_bounds__(256) void seg_max_kernel(
    const int* __restrict__ sources, const int* __restrict__ targets,
    const uint4* __restrict__ t_pk4, unsigned* __restrict__ m_u, int E)
{
    int e = blockIdx.x * 256 + threadIdx.x;
    if (e >= E) return;
    int s  = __builtin_nontemporal_load(sources + e);
    int tg = __builtin_nontemporal_load(targets + e);
    uint4 tv = t_pk4[s];
    unsigned* mp = m_u + (size_t)tg * HD;
    const uint4* m4 = (const uint4*)mp;
    uint4 c0 = m4[0];
    uint4 c1 = m4[1];
    unsigned f;
    f = fmap(bf_lo(tv.x)); if (f > c0.x) atomicMax(mp + 0, f);
    f = fmap(bf_hi(tv.x)); if (f > c0.y) atomicMax(mp + 1, f);
    f = fmap(bf_lo(tv.y)); if (f > c0.z) atomicMax(mp + 2, f);
    f = fmap(bf_hi(tv.y)); if (f > c0.w) atomicMax(mp + 3, f);
    f = fmap(bf_lo(tv.z)); if (f > c1.x) atomicMax(mp + 4, f);
    f = fmap(bf_hi(tv.z)); if (f > c1.y) atomicMax(mp + 5, f);
    f = fmap(bf_lo(tv.w)); if (f > c1.z) atomicMax(mp + 6, f);
    f = fmap(bf_hi(tv.w)); if (f > c1.w) atomicMax(mp + 7, f);
}

__global__ __launch_bounds__(256) void pack_m_kernel(
    const unsigned* __restrict__ m_u, uint4* __restrict__ m_pk, int N)
{
    int n = blockIdx.x * 256 + threadIdx.x;
    if (n >= N) return;
    const uint4* mu4 = (const uint4*)m_u + (size_t)n * 2;
    uint4 c0 = mu4[0];
    uint4 c1 = mu4[1];
    uint4 o;
    o.x = (__float_as_uint(funmap(c0.x)) >> 16) | (__float_as_uint(funmap(c0.y)) & 0xFFFF0000u);
    o.y = (__float_as_uint(funmap(c0.z)) >> 16) | (__float_as_uint(funmap(c0.w)) & 0xFFFF0000u);
    o.z = (__float_as_uint(funmap(c1.x)) >> 16) | (__float_as_uint(funmap(c1.y)) & 0xFFFF0000u);
    o.w = (__float_as_uint(funmap(c1.z)) >> 16) | (__float_as_uint(funmap(c1.w)) & 0xFFFF0000u);
    m_pk[n] = o;
}

// Phase C: out[e,h] = exp(t[src,h] - m[tgt,h]) * drop_mask[e,h].
// (Reference's s = segment_max(exp(ef-m)) + 1e-9 == 1.0f exactly in fp32.)
// dm loads / out stores are CACHEABLE (not NT): each instruction is 16B/lane at 32B
// stride, so only L2 can merge the two half-line passes; NT bypassed that merge.
__global__ __launch_bounds__(256) void finalize_kernel(
    const int* __restrict__ sources, const int* __restrict__ targets,
    const uint4* __restrict__ t_pk4, const uint4* __restrict__ m_pk,
    const float* __restrict__ dm, float* __restrict__ out, int E)
{
    int e = blockIdx.x * 256 + threadIdx.x;
    if (e >= E) return;
    int s  = __builtin_nontemporal_load(sources + e);
    int tg = __builtin_nontemporal_load(targets + e);
    uint4 tv = t_pk4[s];
    uint4 mv = m_pk[tg];
    const vf4* dm4 = (const vf4*)dm;
    vf4 d0 = dm4[(size_t)e * 2];      // heads 0..3
    vf4 d1 = dm4[(size_t)e * 2 + 1];  // heads 4..7
    vf4 o0, o1;
    o0.x = expf(bf_lo(tv.x) - bf_lo(mv.x)) * d0.x;  // h0
    o0.y = expf(bf_lo(tv.y) - bf_lo(mv.y)) * d0.y;  // h1
    o0.z = expf(bf_lo(tv.z) - bf_lo(mv.z)) * d0.z;  // h2
    o0.w = expf(bf_lo(tv.w) - bf_lo(mv.w)) * d0.w;  // h3
    o1.x = expf(bf_hi(tv.x) - bf_hi(mv.x)) * d1.x;  // h4
    o1.y = expf(bf_hi(tv.y) - bf_hi(mv.y)) * d1.y;  // h5
    o1.z = expf(bf_hi(tv.z) - bf_hi(mv.z)) * d1.z;  // h6
    o1.w = expf(bf_hi(tv.w) - bf_hi(mv.w)) * d1.w;  // h7
    vf4* out4 = (vf4*)out;
    out4[(size_t)e * 2]     = o0;
    out4[(size_t)e * 2 + 1] = o1;
}

extern "C" void kernel_launch(void* const* d_in, const int* in_sizes, int n_in,
                              void* d_out, int out_size, void* d_ws, size_t ws_size,
                              hipStream_t stream)
{
    const float* X       = (const float*)d_in[0];   // (B,N,H,D) fp32
    const float* Wk      = (const float*)d_in[1];   // (D,H,1)   fp32
    const int*   targets = (const int*)d_in[2];     // (B,E)
    const int*   sources = (const int*)d_in[3];     // (B,E)
    const float* dm      = (const float*)d_in[5];   // (B,E,H)

    int E = in_sizes[2];          // B=1
    int N = in_sizes[4];          // degree is (B,N)

    float* out = (float*)d_out;
    int blocksA = (N + 7) / 8;           // 4 waves/block, 2 nodes/wave
    int blocksE = (E + 255) / 256;

    // New-path workspace layout (bytes):
    //   t_pk 16N | m_u 32N | m_pk 16N | cnt 4N | lst CAP*4*N = 256N   -> total 324N
    size_t needed = (size_t)N * 324;

    char* w = (char*)d_ws;
    unsigned* t_pk = (unsigned*)w;
    unsigned* m_u  = (unsigned*)(w + (size_t)N * 16);
    uint4*    m_pk = (uint4*)  (w + (size_t)N * 48);

    if (ws_size >= needed) {
        unsigned* cnt = (unsigned*)(w + (size_t)N * 64);
        unsigned* lst = (unsigned*)(w + (size_t)N * 68);

        attn_tanh_kernel<<<blocksA, 256, 0, stream>>>(X, Wk, t_pk, (uint2*)m_u, cnt, N);
        int blocksE2 = (E + 511) / 512;  // 2 edges/thread
        scatter_kernel<<<blocksE2, 256, 0, stream>>>(sources, targets, cnt, lst,
                                                     (const uint4*)t_pk, m_u, N, E);
        int blocksG = (N + 3) / 4;       // one wave per node
        gather_max_kernel<<<blocksG, 256, 0, stream>>>(cnt, lst, (const uint4*)t_pk,
                                                       m_u, m_pk, N);
        finalize_kernel<<<blocksE, 256, 0, stream>>>(sources, targets, (const uint4*)t_pk,
                                                     m_pk, dm, out, E);
    } else {
        // Fallback: previous proven path (identical numerics).
        attn_tanh_kernel<<<blocksA, 256, 0, stream>>>(X, Wk, t_pk, (uint2*)m_u, nullptr, N);
        seg_max_kernel<<<blocksE, 256, 0, stream>>>(sources, targets, (const uint4*)t_pk, m_u, E);
        int blocksN = (N + 255) / 256;
        pack_m_kernel<<<blocksN, 256, 0, stream>>>(m_u, m_pk, N);
        finalize_kernel<<<blocksE, 256, 0, stream>>>(sources, targets, (const uint4*)t_pk,
                                                     m_pk, dm, out, E);
    }
}

// Round 4
// 530.517 us; speedup vs baseline: 1.3295x; 1.3222x over previous
//
#include <hip/hip_runtime.h>
#include <stdint.h>

#define HD 8
#define DD 64
#define BSHIFT 9            // bucket covers 512 consecutive target nodes
#define BRANGE 512
#define NBMAX 256

// Native clang vector types.
typedef float  vf4 __attribute__((ext_vector_type(4)));

// Monotone float->uint mapping so unsigned atomicMax implements float max.
__device__ __forceinline__ unsigned fmap(float f) {
    unsigned u = __float_as_uint(f);
    return u ^ (unsigned)(((int)u >> 31) | 0x80000000);
}
__device__ __forceinline__ float funmap(unsigned u) {
    u ^= ((int)u < 0) ? 0x80000000u : 0xFFFFFFFFu;
    return __uint_as_float(u);
}
#define FMAP_NEG_INF 0x007FFFFFu   // maps back to -inf

// bf16 helpers. Slot layout per node (4 u32 words): word g = (bf16 h=g) | (bf16 h=g+4)<<16.
__device__ __forceinline__ unsigned pack_bf16_rne(float a, float b) {
    unsigned ua = __float_as_uint(a); ua += 0x7FFF + ((ua >> 16) & 1);
    unsigned ub = __float_as_uint(b); ub += 0x7FFF + ((ub >> 16) & 1);
    return (ua >> 16) | (ub & 0xFFFF0000u);
}
__device__ __forceinline__ float bf_lo(unsigned u) { return __uint_as_float(u << 16); }
__device__ __forceinline__ float bf_hi(unsigned u) { return __uint_as_float(u & 0xFFFF0000u); }

// Phase A: t_pk[n] = packed bf16 tanh(X[n,h,:] . W[:,h]); init m_u slots to mapped(-inf);
// zero the NB per-bucket record counters. X loads are CACHEABLE now (NT suspected of
// throttling streaming BW to ~1 TB/s; the 6.3 TB/s ceiling was measured with plain loads).
__global__ __launch_bounds__(256) void attn_tanh_kernel(
    const float* __restrict__ X, const float* __restrict__ Wk,
    unsigned* __restrict__ t_pk, uint2* __restrict__ m_init,
    unsigned* __restrict__ gcnt, int NB, int N)
{
    __shared__ float Ws[DD * HD];   // W[d*8+h], 2 KB
    int tid = threadIdx.x;
    for (int i = tid; i < DD * HD; i += 256) Ws[i] = Wk[i];

    int gid = blockIdx.x * 256 + tid;
    if (gcnt != nullptr && gid < NB) gcnt[gid] = 0;

    __syncthreads();

    int wave = tid >> 6, lane = tid & 63;
    int n0 = (blockIdx.x * 4 + wave) * 2;
    if (n0 >= N) return;
    bool two = (n0 + 1 < N);

    const vf4* Xa = (const vf4*)X + (size_t)n0 * 128;  // 512 floats/node
    vf4 z = {0.f, 0.f, 0.f, 0.f};
    vf4 xv0 = Xa[lane];
    vf4 xv1 = Xa[64 + lane];
    vf4 xv2 = two ? Xa[128 + lane] : z;
    vf4 xv3 = two ? Xa[192 + lane] : z;

    int h0 = lane >> 4, d0 = (lane & 15) << 2;
    int h1 = 4 + h0;
    float w00 = Ws[(d0 + 0) * HD + h0], w01 = Ws[(d0 + 1) * HD + h0],
          w02 = Ws[(d0 + 2) * HD + h0], w03 = Ws[(d0 + 3) * HD + h0];
    float w10 = Ws[(d0 + 0) * HD + h1], w11 = Ws[(d0 + 1) * HD + h1],
          w12 = Ws[(d0 + 2) * HD + h1], w13 = Ws[(d0 + 3) * HD + h1];

    float p0 = xv0.x * w00 + xv0.y * w01 + xv0.z * w02 + xv0.w * w03;
    float p1 = xv1.x * w10 + xv1.y * w11 + xv1.z * w12 + xv1.w * w13;
    float p2 = xv2.x * w00 + xv2.y * w01 + xv2.z * w02 + xv2.w * w03;
    float p3 = xv3.x * w10 + xv3.y * w11 + xv3.z * w12 + xv3.w * w13;

    for (int off = 8; off; off >>= 1) {
        p0 += __shfl_xor(p0, off);
        p1 += __shfl_xor(p1, off);
        p2 += __shfl_xor(p2, off);
        p3 += __shfl_xor(p3, off);
    }
    if ((lane & 15) == 0) {
        int g = lane >> 4;
        t_pk[(size_t)n0 * 4 + g] = pack_bf16_rne(tanhf(p0), tanhf(p1));
        m_init[(size_t)n0 * 4 + g] = make_uint2(FMAP_NEG_INF, FMAP_NEG_INF);
        if (two) {
            t_pk[(size_t)(n0 + 1) * 4 + g] = pack_bf16_rne(tanhf(p2), tanhf(p3));
            m_init[(size_t)(n0 + 1) * 4 + g] = make_uint2(FMAP_NEG_INF, FMAP_NEG_INF);
        }
    }
}

// Pass 1: bin edges by target bucket (tgt>>9). Per block of 4096 edges: LDS histogram,
// one global atomicAdd per touched bucket to reserve space, then write packed 4B records
// ((tgt&511)<<SRC_BITS | src) into contiguous bucket regions. Per-block open-line set is
// ~NB*64B = 12.5 KB -> L2-collected, near-full-line writebacks. Overflow (cap exceeded,
// ~never: cap = mean+65sigma) falls back to exact global atomicMax into m_u.
__global__ __launch_bounds__(256) void bin_kernel(
    const int* __restrict__ sources, const int* __restrict__ targets,
    unsigned* __restrict__ gcnt, unsigned* __restrict__ buf,
    const uint4* __restrict__ t_pk4, unsigned* __restrict__ m_u,
    int NB, int CAPB, int SRC_BITS, int E)
{
    __shared__ unsigned hist[NBMAX];
    __shared__ unsigned base[NBMAX];
    __shared__ unsigned cur[NBMAX];
    int tid = threadIdx.x;
    if (tid < NB) { hist[tid] = 0; cur[tid] = 0; }
    __syncthreads();

    int e0 = blockIdx.x * 4096;
    #pragma unroll
    for (int k = 0; k < 16; ++k) {
        int e = e0 + k * 256 + tid;
        if (e < E) {
            int tg = targets[e];
            atomicAdd(&hist[tg >> BSHIFT], 1u);
        }
    }
    __syncthreads();
    if (tid < NB && hist[tid] != 0)
        base[tid] = atomicAdd(gcnt + tid, hist[tid]);
    __syncthreads();

    #pragma unroll
    for (int k = 0; k < 16; ++k) {
        int e = e0 + k * 256 + tid;
        if (e < E) {
            int tg = targets[e];
            int s  = sources[e];           // chunk is L2-hot from the count pass
            int b  = tg >> BSHIFT;
            unsigned pos = base[b] + atomicAdd(&cur[b], 1u);
            if (pos < (unsigned)CAPB) {
                buf[(size_t)b * CAPB + pos] =
                    ((unsigned)(tg & (BRANGE - 1)) << SRC_BITS) | (unsigned)s;
            } else {
                uint4 tv = t_pk4[s];
                unsigned* mp = m_u + (size_t)tg * HD;
                atomicMax(mp + 0, fmap(bf_lo(tv.x)));
                atomicMax(mp + 1, fmap(bf_hi(tv.x)));
                atomicMax(mp + 2, fmap(bf_lo(tv.y)));
                atomicMax(mp + 3, fmap(bf_hi(tv.y)));
                atomicMax(mp + 4, fmap(bf_lo(tv.z)));
                atomicMax(mp + 5, fmap(bf_hi(tv.z)));
                atomicMax(mp + 6, fmap(bf_lo(tv.w)));
                atomicMax(mp + 7, fmap(bf_hi(tv.w)));
            }
        }
    }
}

// Pass 2: one block per bucket. 16 KB LDS max-table (512 nodes x 8 heads, fmap'd u32);
// stream the bucket's contiguous records, gather t_pk4[src] (L2-resident), LDS atomicMax;
// then coalesced m_pk write, merging m_u (only non -inf if the overflow path fired).
__global__ __launch_bounds__(256) void reduce_kernel(
    const unsigned* __restrict__ gcnt, const unsigned* __restrict__ buf,
    const uint4* __restrict__ t_pk4, const unsigned* __restrict__ m_u,
    uint4* __restrict__ m_pk, int CAPB, int SRC_BITS, int N)
{
    __shared__ unsigned mt[BRANGE * HD];   // 16 KB
    int tid = threadIdx.x;
    int b = blockIdx.x;
    for (int i = tid; i < BRANGE * HD; i += 256) mt[i] = FMAP_NEG_INF;
    __syncthreads();

    unsigned cnt = gcnt[b];
    if (cnt > (unsigned)CAPB) cnt = CAPB;
    unsigned srcmask = (1u << SRC_BITS) - 1;
    const unsigned* bb = buf + (size_t)b * CAPB;

    for (unsigned i = tid; i < cnt; i += 256) {
        unsigned rec = bb[i];
        unsigned s  = rec & srcmask;
        unsigned tl = rec >> SRC_BITS;
        uint4 tv = t_pk4[s];
        unsigned* mp = mt + tl * HD;
        atomicMax(mp + 0, fmap(bf_lo(tv.x)));
        atomicMax(mp + 1, fmap(bf_hi(tv.x)));
        atomicMax(mp + 2, fmap(bf_lo(tv.y)));
        atomicMax(mp + 3, fmap(bf_hi(tv.y)));
        atomicMax(mp + 4, fmap(bf_lo(tv.z)));
        atomicMax(mp + 5, fmap(bf_hi(tv.z)));
        atomicMax(mp + 6, fmap(bf_lo(tv.w)));
        atomicMax(mp + 7, fmap(bf_hi(tv.w)));
    }
    __syncthreads();

    int n0 = b << BSHIFT;
    for (int tl = tid; tl < BRANGE; tl += 256) {
        int n = n0 + tl;
        if (n < N) {
            const unsigned* ms = mt + tl * HD;
            const unsigned* mu = m_u + (size_t)n * HD;
            float v0 = fmaxf(funmap(ms[0]), funmap(mu[0]));
            float v1 = fmaxf(funmap(ms[1]), funmap(mu[1]));
            float v2 = fmaxf(funmap(ms[2]), funmap(mu[2]));
            float v3 = fmaxf(funmap(ms[3]), funmap(mu[3]));
            float v4 = fmaxf(funmap(ms[4]), funmap(mu[4]));
            float v5 = fmaxf(funmap(ms[5]), funmap(mu[5]));
            float v6 = fmaxf(funmap(ms[6]), funmap(mu[6]));
            float v7 = fmaxf(funmap(ms[7]), funmap(mu[7]));
            uint4 o;                       // lossless: maxes of bf16 values
            o.x = pack_bf16_rne(v0, v1);
            o.y = pack_bf16_rne(v2, v3);
            o.z = pack_bf16_rne(v4, v5);
            o.w = pack_bf16_rne(v6, v7);
            m_pk[n] = o;
        }
    }
}

// ---- Fallback path (old, proven) kernels: used only if packing/workspace fails ----

__global__ __launch_bounds__(256) void seg_max_kernel(
    const int* __restrict__ sources, const int* __restrict__ targets,
    const uint4* __restrict__ t_pk4, unsigned* __restrict__ m_u, int E)
{
    int e = blockIdx.x * 256 + threadIdx.x;
    if (e >= E) return;
    int s  = __builtin_nontemporal_load(sources + e);
    int tg = __builtin_nontemporal_load(targets + e);
    uint4 tv = t_pk4[s];
    unsigned* mp = m_u + (size_t)tg * HD;
    const uint4* m4 = (const uint4*)mp;
    uint4 c0 = m4[0];
    uint4 c1 = m4[1];
    unsigned f;
    f = fmap(bf_lo(tv.x)); if (f > c0.x) atomicMax(mp + 0, f);
    f = fmap(bf_hi(tv.x)); if (f > c0.y) atomicMax(mp + 1, f);
    f = fmap(bf_lo(tv.y)); if (f > c0.z) atomicMax(mp + 2, f);
    f = fmap(bf_hi(tv.y)); if (f > c0.w) atomicMax(mp + 3, f);
    f = fmap(bf_lo(tv.z)); if (f > c1.x) atomicMax(mp + 4, f);
    f = fmap(bf_hi(tv.z)); if (f > c1.y) atomicMax(mp + 5, f);
    f = fmap(bf_lo(tv.w)); if (f > c1.z) atomicMax(mp + 6, f);
    f = fmap(bf_hi(tv.w)); if (f > c1.w) atomicMax(mp + 7, f);
}

__global__ __launch_bounds__(256) void pack_m_kernel(
    const unsigned* __restrict__ m_u, uint4* __restrict__ m_pk, int N)
{
    int n = blockIdx.x * 256 + threadIdx.x;
    if (n >= N) return;
    const uint4* mu4 = (const uint4*)m_u + (size_t)n * 2;
    uint4 c0 = mu4[0];
    uint4 c1 = mu4[1];
    uint4 o;
    o.x = (__float_as_uint(funmap(c0.x)) >> 16) | (__float_as_uint(funmap(c0.y)) & 0xFFFF0000u);
    o.y = (__float_as_uint(funmap(c0.z)) >> 16) | (__float_as_uint(funmap(c0.w)) & 0xFFFF0000u);
    o.z = (__float_as_uint(funmap(c1.x)) >> 16) | (__float_as_uint(funmap(c1.y)) & 0xFFFF0000u);
    o.w = (__float_as_uint(funmap(c1.z)) >> 16) | (__float_as_uint(funmap(c1.w)) & 0xFFFF0000u);
    m_pk[n] = o;
}

// Phase C: out[e,h] = exp(t[src,h] - m[tgt,h]) * drop_mask[e,h].
// (Reference's s = segment_max(exp(ef-m)) + 1e-9 == 1.0f exactly in fp32.)
__global__ __launch_bounds__(256) void finalize_kernel(
    const int* __restrict__ sources, const int* __restrict__ targets,
    const uint4* __restrict__ t_pk4, const uint4* __restrict__ m_pk,
    const float* __restrict__ dm, float* __restrict__ out, int E)
{
    int e = blockIdx.x * 256 + threadIdx.x;
    if (e >= E) return;
    int s  = __builtin_nontemporal_load(sources + e);
    int tg = __builtin_nontemporal_load(targets + e);
    uint4 tv = t_pk4[s];
    uint4 mv = m_pk[tg];
    const vf4* dm4 = (const vf4*)dm;
    vf4 d0 = dm4[(size_t)e * 2];      // heads 0..3
    vf4 d1 = dm4[(size_t)e * 2 + 1];  // heads 4..7
    vf4 o0, o1;
    o0.x = expf(bf_lo(tv.x) - bf_lo(mv.x)) * d0.x;  // h0
    o0.y = expf(bf_lo(tv.y) - bf_lo(mv.y)) * d0.y;  // h1
    o0.z = expf(bf_lo(tv.z) - bf_lo(mv.z)) * d0.z;  // h2
    o0.w = expf(bf_lo(tv.w) - bf_lo(mv.w)) * d0.w;  // h3
    o1.x = expf(bf_hi(tv.x) - bf_hi(mv.x)) * d1.x;  // h4
    o1.y = expf(bf_hi(tv.y) - bf_hi(mv.y)) * d1.y;  // h5
    o1.z = expf(bf_hi(tv.z) - bf_hi(mv.z)) * d1.z;  // h6
    o1.w = expf(bf_hi(tv.w) - bf_hi(mv.w)) * d1.w;  // h7
    vf4* out4 = (vf4*)out;
    out4[(size_t)e * 2]     = o0;
    out4[(size_t)e * 2 + 1] = o1;
}

extern "C" void kernel_launch(void* const* d_in, const int* in_sizes, int n_in,
                              void* d_out, int out_size, void* d_ws, size_t ws_size,
                              hipStream_t stream)
{
    const float* X       = (const float*)d_in[0];   // (B,N,H,D) fp32
    const float* Wk      = (const float*)d_in[1];   // (D,H,1)   fp32
    const int*   targets = (const int*)d_in[2];     // (B,E)
    const int*   sources = (const int*)d_in[3];     // (B,E)
    const float* dm      = (const float*)d_in[5];   // (B,E,H)

    int E = in_sizes[2];          // B=1
    int N = in_sizes[4];          // degree is (B,N)

    float* out = (float*)d_out;
    int blocksA = (N + 7) / 8;           // 4 waves/block, 2 nodes/wave
    int blocksE = (E + 255) / 256;

    // Binned-path parameters.
    int NB = (N + BRANGE - 1) >> BSHIFT;              // buckets of 512 nodes
    int SRC_BITS = 1;
    while ((1 << SRC_BITS) < N && SRC_BITS < 31) ++SRC_BITS;
    bool packable = (NB <= NBMAX) && (SRC_BITS + BSHIFT <= 32);
    long long capll = ((long long)(E + NB - 1) / (NB > 0 ? NB : 1));
    capll = (capll * 3) / 2;                          // mean * 1.5 (= mean + ~65 sigma)
    capll = (capll + 255) & ~255LL;
    int CAPB = (int)capll;

    // Workspace layout (bytes): t_pk 16N | m_u 32N | m_pk 16N | gcnt 4N | buf NB*CAPB*4
    size_t needed = (size_t)N * 68 + (size_t)NB * (size_t)CAPB * 4;

    char* w = (char*)d_ws;
    unsigned* t_pk = (unsigned*)w;
    unsigned* m_u  = (unsigned*)(w + (size_t)N * 16);
    uint4*    m_pk = (uint4*)  (w + (size_t)N * 48);

    if (packable && ws_size >= needed) {
        unsigned* gcnt = (unsigned*)(w + (size_t)N * 64);
        unsigned* buf  = (unsigned*)(w + (size_t)N * 68);

        attn_tanh_kernel<<<blocksA, 256, 0, stream>>>(X, Wk, t_pk, (uint2*)m_u, gcnt, NB, N);
        int blocksB = (E + 4095) / 4096;
        bin_kernel<<<blocksB, 256, 0, stream>>>(sources, targets, gcnt, buf,
                                                (const uint4*)t_pk, m_u, NB, CAPB, SRC_BITS, E);
        reduce_kernel<<<NB, 256, 0, stream>>>(gcnt, buf, (const uint4*)t_pk, m_u,
                                              m_pk, CAPB, SRC_BITS, N);
        finalize_kernel<<<blocksE, 256, 0, stream>>>(sources, targets, (const uint4*)t_pk,
                                                     m_pk, dm, out, E);
    } else {
        // Fallback: proven atomicMax path (identical numerics).
        attn_tanh_kernel<<<blocksA, 256, 0, stream>>>(X, Wk, t_pk, (uint2*)m_u, nullptr, 0, N);
        seg_max_kernel<<<blocksE, 256, 0, stream>>>(sources, targets, (const uint4*)t_pk, m_u, E);
        int blocksN = (N + 255) / 256;
        pack_m_kernel<<<blocksN, 256, 0, stream>>>(m_u, m_pk, N);
        finalize_kernel<<<blocksE, 256, 0, stream>>>(sources, targets, (const uint4*)t_pk,
                                                     m_pk, dm, out, E);
    }
}